// Round 5
// baseline (1026.823 us; speedup 1.0000x reference)
//
#include <hip/hip_runtime.h>
#include <math.h>

typedef short  bf16x8 __attribute__((ext_vector_type(8)));
typedef float  f32x4  __attribute__((ext_vector_type(4)));

#define DIM   1024
#define RANK  256
#define NROWS 16
#define NT    1024
#define NWAVE 16
#define TOTAL_ROWS 4096
#define OUT_HALF (TOTAL_ROWS*DIM)

// LDS byte layout
#define VS_OFF   0            // ushort[16][1024], XOR-swizzled rows (32768)
#define H2_OFF   32768        // ushort[16][256],  XOR-swizzled rows (8192)
#define GS_OFF   40960        // ushort[16][1032]  pitch 2064 B (33024)
#define GS_PITCH 2064
#define WS_OFF   73984        // float[16][16] (1024)
#define SG_OFF   75008        // float[16]     (64)
#define SMEM_BYTES 75072

static constexpr double XI  = 0.1786178958448091;
static constexpr double LAM = -0.2123418310626054;
static constexpr double CHI = -0.0662645826698185;

__device__ __forceinline__ unsigned short f2bf(float f) {
    unsigned u = __builtin_bit_cast(unsigned, f);
    u += 0x7FFFu + ((u >> 16) & 1u);        // round-to-nearest-even
    return (unsigned short)(u >> 16);
}
__device__ __forceinline__ float bf2f(unsigned short b) {
    return __builtin_bit_cast(float, ((unsigned)b) << 16);
}

// swizzle: byte ^= (row&7)<<4 -> 16 A-rows spread over 8 16B slots
__device__ __forceinline__ int vs_addr(int m, int kb) {
    return VS_OFF + ((m * 2048 + kb) ^ ((m & 7) << 4));
}
__device__ __forceinline__ int h2_addr(int m, int kb) {
    return H2_OFF + ((m * 512 + kb) ^ ((m & 7) << 4));
}

// ---- prep: pack U,W (fp32) into bf16 MFMA B-fragment order in d_ws ----
// B-frag 16x16x32: lane l holds B[k = kt*32 + (l>>4)*8 + j][n = nt*16 + (l&15)]
// U slot = kt*16+nt (kt<32,nt<16); W slot = 512 + kt*64+nt (kt<8,nt<64)
__global__ __launch_bounds__(256)
void prep_pack(const float* __restrict__ U, const float* __restrict__ Wm,
               bf16x8* __restrict__ pk)
{
    const int tid  = blockIdx.x * 256 + threadIdx.x;   // 0..65535
    const int lane = tid & 63;
    const int frag = tid >> 6;                          // 0..1023
    bf16x8 o;
    if (frag < 512) {
        const int kt = frag >> 4, nt = frag & 15;
        const int krow = kt * 32 + (lane >> 4) * 8;
        const int n    = nt * 16 + (lane & 15);
        #pragma unroll
        for (int j = 0; j < 8; ++j) o[j] = (short)f2bf(U[(krow + j) * RANK + n]);
    } else {
        const int f = frag - 512;
        const int kt = f >> 6, nt = f & 63;
        const int krow = kt * 32 + (lane >> 4) * 8;
        const int n    = nt * 16 + (lane & 15);
        #pragma unroll
        for (int j = 0; j < 8; ++j) o[j] = (short)f2bf(Wm[(krow + j) * DIM + n]);
    }
    pk[frag * 64 + lane] = o;
}

__global__ __launch_bounds__(NT, 4)
void omelyan_mfma(const float* __restrict__ x_in,
                  const float* __restrict__ v_in,
                  const float* __restrict__ force,
                  const float* __restrict__ Vw,
                  const int* __restrict__ steps_p,
                  const bf16x8* __restrict__ pk,
                  float* __restrict__ out)
{
    extern __shared__ char smem[];
    float* wsums = (float*)(smem + WS_OFF);
    float* sings = (float*)(smem + SG_OFF);

    const int t    = threadIdx.x;        // 0..1023
    const int lane = t & 63;
    const int w    = t >> 6;             // 0..15
    const int row0 = blockIdx.x * NROWS;
    const int nsteps = steps_p[0];

    const float dt = 0.01f;

    // per-thread elementwise state: element (m, d = t)
    float xr[NROWS], vr[NROWS], fr[NROWS];
    const float vw = Vw[t];

    #pragma unroll
    for (int m = 0; m < NROWS; ++m) {
        const int base = (row0 + m) * DIM + t;
        xr[m] = x_in[base];
        vr[m] = v_in[base];
        fr[m] = force[base];
        *(unsigned short*)(smem + vs_addr(m, 2 * t)) = f2bf(vr[m]);
    }
    __syncthreads();

    #pragma unroll 1
    for (int step = 0; step < nsteps; ++step) {
        #pragma unroll 1
        for (int sub = 0; sub < 4; ++sub) {
            const float cdt = dt * (sub == 0 ? (float)XI :
                                    sub == 1 ? (float)CHI :
                                    sub == 2 ? (float)(1.0 - 2.0 * (CHI + XI)) :
                                               (float)CHI);
            const float ddt = dt * ((sub == 0 || sub == 3)
                                    ? (float)((1.0 - 2.0 * LAM) * 0.5)
                                    : (float)LAM);

            // ---- drift x + r2 partial (no barrier here: folded into b2) ----
            #pragma unroll
            for (int m = 0; m < NROWS; ++m) {
                xr[m] = fmaf(cdt, vr[m], xr[m]);
                float s = xr[m] * xr[m];
                #pragma unroll
                for (int off = 32; off >= 1; off >>= 1) s += __shfl_xor(s, off, 64);
                if (lane == 0) wsums[m * NWAVE + w] = s;
            }

            // ---- H: h = v @ U (M=16,N=256,K=1024); wave owns n-tile w ----
            {
                f32x4 hacc = {0.f, 0.f, 0.f, 0.f};
                bf16x8 bb[8];                           // ring-8 prefetch
                #pragma unroll
                for (int s = 0; s < 8; ++s)
                    bb[s] = pk[(s * 16 + w) * 64 + lane];
                bf16x8 areg[2];
                areg[0] = *(const bf16x8*)(smem + vs_addr(lane & 15, (lane >> 4) * 16));
                #pragma unroll
                for (int ks = 0; ks < 32; ++ks) {
                    if (ks + 1 < 32)
                        areg[(ks + 1) & 1] = *(const bf16x8*)(smem + vs_addr(lane & 15, (ks + 1) * 64 + (lane >> 4) * 16));
                    hacc = __builtin_amdgcn_mfma_f32_16x16x32_bf16(areg[ks & 1], bb[ks & 7], hacc, 0, 0, 0);
                    if (ks + 8 < 32)
                        bb[ks & 7] = pk[((ks + 8) * 16 + w) * 64 + lane];
                }
                // h2 = (h*h) bf16, swizzled; D: col=lane&15, row=(lane>>4)*4+r
                #pragma unroll
                for (int r = 0; r < 4; ++r) {
                    const int m = (lane >> 4) * 4 + r;
                    const int n = w * 16 + (lane & 15);
                    *(unsigned short*)(smem + h2_addr(m, 2 * n)) = f2bf(hacc[r] * hacc[r]);
                }
            }
            __syncthreads();                            // b2 (covers wsums + h2)

            if (t < NROWS) {
                float r2 = 0.f;
                #pragma unroll
                for (int q = 0; q < NWAVE; ++q) r2 += wsums[t * NWAVE + q];
                sings[t] = 1.f + exp2f(-r2 * 1.4426950408889634f);
            }

            // ---- G: gamma = h2 @ W (M=16,N=1024,K=256); wave owns 4 n-tiles ----
            {
                f32x4 g[4];
                #pragma unroll
                for (int i = 0; i < 4; ++i) g[i] = (f32x4){0.f, 0.f, 0.f, 0.f};
                bf16x8 wb[8];                           // ring-8 over micro-stream
                #pragma unroll
                for (int u = 0; u < 8; ++u) {
                    const int kk = u >> 2, i = u & 3;
                    wb[u] = pk[(512 + kk * 64 + w * 4 + i) * 64 + lane];
                }
                bf16x8 areg[2];
                areg[0] = *(const bf16x8*)(smem + h2_addr(lane & 15, (lane >> 4) * 16));
                #pragma unroll
                for (int u = 0; u < 32; ++u) {
                    const int kk = u >> 2, i = u & 3;
                    if (i == 0 && kk + 1 < 8)
                        areg[(kk + 1) & 1] = *(const bf16x8*)(smem + h2_addr(lane & 15, (kk + 1) * 64 + (lane >> 4) * 16));
                    g[i] = __builtin_amdgcn_mfma_f32_16x16x32_bf16(areg[kk & 1], wb[u & 7], g[i], 0, 0, 0);
                    if (u + 8 < 32) {
                        const int u2 = u + 8;
                        const int kk2 = u2 >> 2, i2 = u2 & 3;
                        wb[u & 7] = pk[(512 + kk2 * 64 + w * 4 + i2) * 64 + lane];
                    }
                }
                // gs (bf16): col = (w*4+i)*16 + (lane&15), row = (lane>>4)*4+r
                #pragma unroll
                for (int i = 0; i < 4; ++i) {
                    #pragma unroll
                    for (int r = 0; r < 4; ++r) {
                        const int m = (lane >> 4) * 4 + r;
                        const int col = (w * 4 + i) * 16 + (lane & 15);
                        *(unsigned short*)(smem + GS_OFF + m * GS_PITCH + col * 2) = f2bf(g[i][r]);
                    }
                }
            }
            __syncthreads();                            // b3 (covers gs + sings)

            // ---- kick: v += ddt*(force - gamma*gate*sing); refresh vs ----
            #pragma unroll
            for (int m = 0; m < NROWS; ++m) {
                const float gmm = bf2f(*(const unsigned short*)(smem + GS_OFF + m * GS_PITCH + 2 * t));
                const float sing = sings[m];
                const float z  = xr[m] * vw;
                const float e  = exp2f(z * 2.885390081777927f);   // e^(2z)
                const float th = 1.f - 2.f / (e + 1.f);           // tanh(z)
                const float gate = fmaf(0.1f, th, 1.f);
                const float a = fr[m] - gmm * gate * sing;
                vr[m] = fmaf(ddt, a, vr[m]);
                *(unsigned short*)(smem + vs_addr(m, 2 * t)) = f2bf(vr[m]);
            }
            __syncthreads();                            // b4 (vs ready for next H)
        } // sub

        // final drift: x += C5*dt*v
        const float c5dt = dt * (float)XI;
        #pragma unroll
        for (int m = 0; m < NROWS; ++m)
            xr[m] = fmaf(c5dt, vr[m], xr[m]);
    } // step

    // ---- store (x, v) ----
    #pragma unroll
    for (int m = 0; m < NROWS; ++m) {
        const int base = (row0 + m) * DIM + t;
        out[base] = xr[m];
        out[OUT_HALF + base] = vr[m];
    }
}

extern "C" void kernel_launch(void* const* d_in, const int* in_sizes, int n_in,
                              void* d_out, int out_size, void* d_ws, size_t ws_size,
                              hipStream_t stream) {
    const float* x_in  = (const float*)d_in[0];
    const float* v_in  = (const float*)d_in[1];
    const float* force = (const float*)d_in[2];
    const float* Umat  = (const float*)d_in[3];
    const float* Wmat  = (const float*)d_in[4];
    const float* Vw    = (const float*)d_in[5];
    const int*   steps = (const int*)d_in[6];
    float* out = (float*)d_out;
    bf16x8* pk = (bf16x8*)d_ws;   // 1 MiB

    (void)hipFuncSetAttribute((const void*)omelyan_mfma,
                              hipFuncAttributeMaxDynamicSharedMemorySize,
                              SMEM_BYTES);

    prep_pack<<<dim3(256), dim3(256), 0, stream>>>(Umat, Wmat, pk);
    omelyan_mfma<<<dim3(TOTAL_ROWS / NROWS), dim3(NT), SMEM_BYTES, stream>>>(
        x_in, v_in, force, Vw, steps, pk, out);
}

// Round 6
// 651.344 us; speedup vs baseline: 1.5765x; 1.5765x over previous
//
#include <hip/hip_runtime.h>
#include <math.h>

typedef short  bf16x8 __attribute__((ext_vector_type(8)));
typedef float  f32x4  __attribute__((ext_vector_type(4)));
typedef float  f32x2  __attribute__((ext_vector_type(2)));

#define DIM   1024
#define RANK  256
#define NROWS 16
#define NT    512
#define NWAVE 8
#define TOTAL_ROWS 4096
#define OUT_HALF (TOTAL_ROWS*DIM)

// LDS byte layout
#define VS_OFF   0            // ushort[16][1024], XOR-swizzled rows (32768)
#define H2_OFF   32768        // ushort[16][256],  XOR-swizzled rows (8192)
#define GS_OFF   40960        // ushort[16][1032]  pitch 2064 B (33024)
#define GS_PITCH 2064
#define WS_OFF   73984        // float[16][8] (512)
#define SG_OFF   74496        // float[16]    (64)
#define SMEM_BYTES 74560

static constexpr double XI  = 0.1786178958448091;
static constexpr double LAM = -0.2123418310626054;
static constexpr double CHI = -0.0662645826698185;

__device__ __forceinline__ unsigned short f2bf(float f) {
    unsigned u = __builtin_bit_cast(unsigned, f);
    u += 0x7FFFu + ((u >> 16) & 1u);        // round-to-nearest-even
    return (unsigned short)(u >> 16);
}
__device__ __forceinline__ float bf2f(unsigned short b) {
    return __builtin_bit_cast(float, ((unsigned)b) << 16);
}

// swizzle: byte ^= (row&7)<<4 -> 16 A-rows spread over 8 16B slots
__device__ __forceinline__ int vs_addr(int m, int kb) {
    return VS_OFF + ((m * 2048 + kb) ^ ((m & 7) << 4));
}
__device__ __forceinline__ int h2_addr(int m, int kb) {
    return H2_OFF + ((m * 512 + kb) ^ ((m & 7) << 4));
}

// ---- prep: pack U,W (fp32) into bf16 MFMA B-fragment order in d_ws ----
// B-frag 16x16x32: lane l holds B[k = kt*32 + (l>>4)*8 + j][n = nt*16 + (l&15)]
// U slot = kt*16+nt (kt<32,nt<16); W slot = 512 + kt*64+nt (kt<8,nt<64)
__global__ __launch_bounds__(256)
void prep_pack(const float* __restrict__ U, const float* __restrict__ Wm,
               bf16x8* __restrict__ pk)
{
    const int tid  = blockIdx.x * 256 + threadIdx.x;   // 0..65535
    const int lane = tid & 63;
    const int frag = tid >> 6;                          // 0..1023
    bf16x8 o;
    if (frag < 512) {
        const int kt = frag >> 4, nt = frag & 15;
        const int krow = kt * 32 + (lane >> 4) * 8;
        const int n    = nt * 16 + (lane & 15);
        #pragma unroll
        for (int j = 0; j < 8; ++j) o[j] = (short)f2bf(U[(krow + j) * RANK + n]);
    } else {
        const int f = frag - 512;
        const int kt = f >> 6, nt = f & 63;
        const int krow = kt * 32 + (lane >> 4) * 8;
        const int n    = nt * 16 + (lane & 15);
        #pragma unroll
        for (int j = 0; j < 8; ++j) o[j] = (short)f2bf(Wm[(krow + j) * DIM + n]);
    }
    pk[frag * 64 + lane] = o;
}

__global__ __launch_bounds__(NT, 1)       // 1 wave/EU min -> HW cap 256 VGPR, no artificial spill
void omelyan_mfma(const float* __restrict__ x_in,
                  const float* __restrict__ v_in,
                  const float* __restrict__ force,
                  const float* __restrict__ Vw,
                  const int* __restrict__ steps_p,
                  const bf16x8* __restrict__ pk,
                  float* __restrict__ out)
{
    extern __shared__ char smem[];
    float* wsums = (float*)(smem + WS_OFF);
    float* sings = (float*)(smem + SG_OFF);

    const int t    = threadIdx.x;        // 0..511
    const int lane = t & 63;
    const int w    = t >> 6;             // 0..7
    const int row0 = blockIdx.x * NROWS;
    const int nsteps = steps_p[0];

    const float dt = 0.01f;

    // per-thread elementwise state: element (m, d = 2t+j), j=0,1
    float xr[NROWS][2], vr[NROWS][2], fr[NROWS][2];
    f32x2 vw = *(const f32x2*)&Vw[2 * t];

    #pragma unroll
    for (int m = 0; m < NROWS; ++m) {
        const int base = (row0 + m) * DIM + 2 * t;
        const f32x2 xv = *(const f32x2*)&x_in[base];
        const f32x2 vv = *(const f32x2*)&v_in[base];
        const f32x2 fv = *(const f32x2*)&force[base];
        xr[m][0] = xv[0]; xr[m][1] = xv[1];
        vr[m][0] = vv[0]; vr[m][1] = vv[1];
        fr[m][0] = fv[0]; fr[m][1] = fv[1];
        const unsigned p = (unsigned)f2bf(vv[0]) | ((unsigned)f2bf(vv[1]) << 16);
        *(unsigned*)(smem + vs_addr(m, 4 * t)) = p;
    }
    __syncthreads();

    #pragma unroll 1
    for (int step = 0; step < nsteps; ++step) {
        #pragma unroll 1
        for (int sub = 0; sub < 4; ++sub) {
            const float cdt = dt * (sub == 0 ? (float)XI :
                                    sub == 1 ? (float)CHI :
                                    sub == 2 ? (float)(1.0 - 2.0 * (CHI + XI)) :
                                               (float)CHI);
            const float ddt = dt * ((sub == 0 || sub == 3)
                                    ? (float)((1.0 - 2.0 * LAM) * 0.5)
                                    : (float)LAM);

            // ---- drift x + r2 partial (barrier folded into b2) ----
            #pragma unroll
            for (int m = 0; m < NROWS; ++m) {
                float s = 0.f;
                #pragma unroll
                for (int j = 0; j < 2; ++j) {
                    xr[m][j] = fmaf(cdt, vr[m][j], xr[m][j]);
                    s = fmaf(xr[m][j], xr[m][j], s);
                }
                #pragma unroll
                for (int off = 32; off >= 1; off >>= 1) s += __shfl_xor(s, off, 64);
                if (lane == 0) wsums[m * NWAVE + w] = s;
            }

            // ---- H: h = v @ U (M=16,N=256,K=1024); wave owns 2 n-tiles ----
            {
                const int nt0 = w * 2;
                f32x4 hacc0 = {0.f,0.f,0.f,0.f}, hacc1 = {0.f,0.f,0.f,0.f};
                bf16x8 bb[8][2];                        // ring-8 prefetch (16 KB in flight)
                #pragma unroll
                for (int s = 0; s < 8; ++s) {
                    bb[s][0] = pk[(s * 16 + nt0 + 0) * 64 + lane];
                    bb[s][1] = pk[(s * 16 + nt0 + 1) * 64 + lane];
                }
                bf16x8 areg[2];
                areg[0] = *(const bf16x8*)(smem + vs_addr(lane & 15, (lane >> 4) * 16));
                #pragma unroll
                for (int ks = 0; ks < 32; ++ks) {
                    if (ks + 1 < 32)
                        areg[(ks + 1) & 1] = *(const bf16x8*)(smem + vs_addr(lane & 15, (ks + 1) * 64 + (lane >> 4) * 16));
                    hacc0 = __builtin_amdgcn_mfma_f32_16x16x32_bf16(areg[ks & 1], bb[ks & 7][0], hacc0, 0, 0, 0);
                    hacc1 = __builtin_amdgcn_mfma_f32_16x16x32_bf16(areg[ks & 1], bb[ks & 7][1], hacc1, 0, 0, 0);
                    if (ks + 8 < 32) {
                        bb[ks & 7][0] = pk[((ks + 8) * 16 + nt0 + 0) * 64 + lane];
                        bb[ks & 7][1] = pk[((ks + 8) * 16 + nt0 + 1) * 64 + lane];
                    }
                }
                // h2 = (h*h) bf16, swizzled; D: col=lane&15, row=(lane>>4)*4+r
                #pragma unroll
                for (int r = 0; r < 4; ++r) {
                    const int m  = (lane >> 4) * 4 + r;
                    const int n0 = (nt0 + 0) * 16 + (lane & 15);
                    const int n1 = (nt0 + 1) * 16 + (lane & 15);
                    *(unsigned short*)(smem + h2_addr(m, 2 * n0)) = f2bf(hacc0[r] * hacc0[r]);
                    *(unsigned short*)(smem + h2_addr(m, 2 * n1)) = f2bf(hacc1[r] * hacc1[r]);
                }
            }
            __syncthreads();                            // b2 (covers wsums + h2)

            if (t < NROWS) {
                float r2 = 0.f;
                #pragma unroll
                for (int q = 0; q < NWAVE; ++q) r2 += wsums[t * NWAVE + q];
                sings[t] = 1.f + exp2f(-r2 * 1.4426950408889634f);
            }

            // ---- G: gamma = h2 @ W (M=16,N=1024,K=256); 2 passes x 4 n-tiles ----
            #pragma unroll 1
            for (int p = 0; p < 2; ++p) {
                const int ntg = w * 8 + p * 4;
                f32x4 g0 = {0.f,0.f,0.f,0.f}, g1 = {0.f,0.f,0.f,0.f};
                f32x4 g2 = {0.f,0.f,0.f,0.f}, g3 = {0.f,0.f,0.f,0.f};
                bf16x8 wb[4][4];                        // ring-4 prefetch (16 KB in flight)
                #pragma unroll
                for (int s = 0; s < 4; ++s)
                    #pragma unroll
                    for (int i = 0; i < 4; ++i)
                        wb[s][i] = pk[512 * 64 + (s * 64 + ntg + i) * 64 + lane];
                bf16x8 areg[2];
                areg[0] = *(const bf16x8*)(smem + h2_addr(lane & 15, (lane >> 4) * 16));
                #pragma unroll
                for (int kk = 0; kk < 8; ++kk) {
                    if (kk + 1 < 8)
                        areg[(kk + 1) & 1] = *(const bf16x8*)(smem + h2_addr(lane & 15, (kk + 1) * 64 + (lane >> 4) * 16));
                    g0 = __builtin_amdgcn_mfma_f32_16x16x32_bf16(areg[kk & 1], wb[kk & 3][0], g0, 0, 0, 0);
                    g1 = __builtin_amdgcn_mfma_f32_16x16x32_bf16(areg[kk & 1], wb[kk & 3][1], g1, 0, 0, 0);
                    g2 = __builtin_amdgcn_mfma_f32_16x16x32_bf16(areg[kk & 1], wb[kk & 3][2], g2, 0, 0, 0);
                    g3 = __builtin_amdgcn_mfma_f32_16x16x32_bf16(areg[kk & 1], wb[kk & 3][3], g3, 0, 0, 0);
                    if (kk + 4 < 8) {
                        #pragma unroll
                        for (int i = 0; i < 4; ++i)
                            wb[kk & 3][i] = pk[512 * 64 + ((kk + 4) * 64 + ntg + i) * 64 + lane];
                    }
                }
                // gs (bf16): col = (ntg+i)*16 + (lane&15), row = (lane>>4)*4+r
                #pragma unroll
                for (int r = 0; r < 4; ++r) {
                    const int m  = (lane >> 4) * 4 + r;
                    const int cb = ntg * 16 + (lane & 15);
                    *(unsigned short*)(smem + GS_OFF + m * GS_PITCH + (cb +  0) * 2) = f2bf(g0[r]);
                    *(unsigned short*)(smem + GS_OFF + m * GS_PITCH + (cb + 16) * 2) = f2bf(g1[r]);
                    *(unsigned short*)(smem + GS_OFF + m * GS_PITCH + (cb + 32) * 2) = f2bf(g2[r]);
                    *(unsigned short*)(smem + GS_OFF + m * GS_PITCH + (cb + 48) * 2) = f2bf(g3[r]);
                }
            }
            __syncthreads();                            // b3 (covers gs + sings)

            // ---- kick: v += ddt*(force - gamma*gate*sing); refresh vs ----
            #pragma unroll
            for (int m = 0; m < NROWS; ++m) {
                const unsigned gu = *(const unsigned*)(smem + GS_OFF + m * GS_PITCH + 4 * t);
                const float gL = bf2f((unsigned short)(gu & 0xFFFFu));
                const float gH = bf2f((unsigned short)(gu >> 16));
                const float sing = sings[m];
                unsigned pp = 0;
                #pragma unroll
                for (int j = 0; j < 2; ++j) {
                    const float g  = j ? gH : gL;
                    const float z  = xr[m][j] * vw[j];
                    const float e  = exp2f(z * 2.885390081777927f);   // e^(2z)
                    const float th = 1.f - 2.f / (e + 1.f);           // tanh(z)
                    const float gate = fmaf(0.1f, th, 1.f);
                    const float a = fr[m][j] - g * gate * sing;
                    vr[m][j] = fmaf(ddt, a, vr[m][j]);
                    pp |= ((unsigned)f2bf(vr[m][j])) << (16 * j);
                }
                *(unsigned*)(smem + vs_addr(m, 4 * t)) = pp;
            }
            __syncthreads();                            // b4 (vs ready for next H)
        } // sub

        // final drift: x += C5*dt*v
        const float c5dt = dt * (float)XI;
        #pragma unroll
        for (int m = 0; m < NROWS; ++m)
            #pragma unroll
            for (int j = 0; j < 2; ++j)
                xr[m][j] = fmaf(c5dt, vr[m][j], xr[m][j]);
    } // step

    // ---- store (x, v) ----
    #pragma unroll
    for (int m = 0; m < NROWS; ++m) {
        const int base = (row0 + m) * DIM + 2 * t;
        f32x2 xo, vo;
        xo[0] = xr[m][0]; xo[1] = xr[m][1];
        vo[0] = vr[m][0]; vo[1] = vr[m][1];
        *(f32x2*)&out[base] = xo;
        *(f32x2*)&out[OUT_HALF + base] = vo;
    }
}

extern "C" void kernel_launch(void* const* d_in, const int* in_sizes, int n_in,
                              void* d_out, int out_size, void* d_ws, size_t ws_size,
                              hipStream_t stream) {
    const float* x_in  = (const float*)d_in[0];
    const float* v_in  = (const float*)d_in[1];
    const float* force = (const float*)d_in[2];
    const float* Umat  = (const float*)d_in[3];
    const float* Wmat  = (const float*)d_in[4];
    const float* Vw    = (const float*)d_in[5];
    const int*   steps = (const int*)d_in[6];
    float* out = (float*)d_out;
    bf16x8* pk = (bf16x8*)d_ws;   // 1 MiB

    (void)hipFuncSetAttribute((const void*)omelyan_mfma,
                              hipFuncAttributeMaxDynamicSharedMemorySize,
                              SMEM_BYTES);

    prep_pack<<<dim3(256), dim3(256), 0, stream>>>(Umat, Wmat, pk);
    omelyan_mfma<<<dim3(TOTAL_ROWS / NROWS), dim3(NT), SMEM_BYTES, stream>>>(
        x_in, v_in, force, Vw, steps, pk, out);
}